// Round 10
// baseline (903.407 us; speedup 1.0000x reference)
//
#include <hip/hip_runtime.h>
#include <hip/hip_bf16.h>

#define Bsz  16384
#define Din  1024
#define Dout 1024
#define Hdim 2048
#define Ecnt 8
#define CNT_PAD 32   // pad expert counters to 128 B apart

typedef _Float16 f16;
typedef _Float16 f16x8 __attribute__((ext_vector_type(8)));
typedef _Float16 f16x4 __attribute__((ext_vector_type(4)));
typedef float    f32x4 __attribute__((ext_vector_type(4)));

#define AS_GLOBAL __attribute__((address_space(1)))
#define AS_LDS    __attribute__((address_space(3)))

__device__ __forceinline__ void async_copy16(const void* gptr, void* lptr) {
    __builtin_amdgcn_global_load_lds(
        (const AS_GLOBAL unsigned int*)gptr,
        (AS_LDS unsigned int*)lptr, 16, 0, 0);
}

#define WAIT_VM(n) do { asm volatile("s_waitcnt vmcnt(" #n ")" ::: "memory"); \
                        __builtin_amdgcn_sched_barrier(0); } while (0)

// ---------------- fp32 -> fp16 cast (W1 / W2 only; x fused into router) ----------------
__global__ __launch_bounds__(256) void cast_kernel(
    const float* __restrict__ in, f16* __restrict__ out)
{
    int i = (blockIdx.x * 256 + threadIdx.x) * 4;
    float4 v = *(const float4*)(in + i);
    f16x4 o;
    o.x = (f16)v.x; o.y = (f16)v.y; o.z = (f16)v.z; o.w = (f16)v.w;
    *(f16x4*)(out + i) = o;
}

// ---------------- Router: logits -> softmax -> top-2 -> buckets (+ fused x->f16 cast) ----------------
__global__ __launch_bounds__(256) void router_kernel(
    const float* __restrict__ x, const float* __restrict__ rW,
    const float* __restrict__ rb, float* __restrict__ probs_out,
    int* __restrict__ cnt, int* __restrict__ bucket, float* __restrict__ gates,
    f16* __restrict__ x16)
{
    __shared__ float s_rw[Ecnt * Din];   // 32 KiB
    __shared__ int   s_e[64];
    __shared__ float s_g[64];
    __shared__ int   s_lpos[64];
    __shared__ int   s_lcnt[Ecnt];
    __shared__ int   s_base[Ecnt];

    int t = threadIdx.x;
    if (t < Ecnt) s_lcnt[t] = 0;
    for (int i = t; i < Ecnt * Din; i += 256) s_rw[i] = rW[i];
    __syncthreads();

    int wid = t >> 6, lane = t & 63;

    float rbv[8];
    #pragma unroll
    for (int e = 0; e < 8; e++) rbv[e] = rb[e];

    #pragma unroll 2
    for (int tt = 0; tt < 8; tt++) {
        int li = wid * 8 + tt;
        int token = blockIdx.x * 32 + li;
        const float* xrow = x + (size_t)token * Din;
        f16* xorow = x16 + (size_t)token * Din;

        float acc[8] = {0,0,0,0,0,0,0,0};
        #pragma unroll
        for (int i = 0; i < 4; i++) {
            int d = i * 256 + lane * 4;
            float4 xv = *(const float4*)(xrow + d);
            f16x4 xo;
            xo.x = (f16)xv.x; xo.y = (f16)xv.y; xo.z = (f16)xv.z; xo.w = (f16)xv.w;
            *(f16x4*)(xorow + d) = xo;
            #pragma unroll
            for (int e = 0; e < 8; e++) {
                float4 wv = *(const float4*)(s_rw + e * Din + d);
                acc[e] += xv.x * wv.x + xv.y * wv.y + xv.z * wv.z + xv.w * wv.w;
            }
        }
        #pragma unroll
        for (int e = 0; e < 8; e++) {
            #pragma unroll
            for (int m = 1; m < 64; m <<= 1) acc[e] += __shfl_xor(acc[e], m, 64);
        }

        float p[8], mx = -1e30f;
        #pragma unroll
        for (int e = 0; e < 8; e++) { p[e] = acc[e] + rbv[e]; mx = fmaxf(mx, p[e]); }
        float s = 0.f;
        #pragma unroll
        for (int e = 0; e < 8; e++) { p[e] = expf(p[e] - mx); s += p[e]; }
        float inv = 1.f / s;
        #pragma unroll
        for (int e = 0; e < 8; e++) p[e] *= inv;

        if (lane == 0) {
            float* po = probs_out + (size_t)token * Ecnt;
            #pragma unroll
            for (int e = 0; e < 8; e++) po[e] = p[e];
            int i0 = 0; float v0 = p[0];
            #pragma unroll
            for (int e = 1; e < 8; e++) if (p[e] > v0) { v0 = p[e]; i0 = e; }
            int i1 = -1; float v1 = -1e30f;
            #pragma unroll
            for (int e = 0; e < 8; e++) if (e != i0 && p[e] > v1) { v1 = p[e]; i1 = e; }
            float invs = 1.f / (v0 + v1);
            s_e[2 * li]     = i0;  s_g[2 * li]     = v0 * invs;
            s_e[2 * li + 1] = i1;  s_g[2 * li + 1] = v1 * invs;
        }
    }
    __syncthreads();

    if (t < 64) s_lpos[t] = atomicAdd(&s_lcnt[s_e[t]], 1);
    __syncthreads();
    if (t < Ecnt) s_base[t] = atomicAdd(&cnt[t * CNT_PAD], s_lcnt[t]);
    __syncthreads();
    if (t < 64) {
        int e = s_e[t];
        int pos = s_base[e] + s_lpos[t];
        int li = t >> 1;
        int token = blockIdx.x * 32 + li;
        bucket[e * Bsz + pos] = token * 2 + (t & 1);
        gates [e * Bsz + pos] = s_g[t];
    }
}

// ---------------- MFMA grouped GEMM: 1 WAVE / 64x64 tile / ZERO barriers ----------------
// R10: every barrier-coupled schedule (R2..R9) pinned MfmaUtil at ~19-22% — the block's
// waves (and the ~2.5 resident blocks) stall in lockstep at each __syncthreads. This
// kernel removes the coupling entirely: one wave per block owns a private dbuf LDS
// (2 x (A 4K + B 4K) = 16.5 KiB), self-synchronized by counted vmcnt — NO barriers in
// the K-loop. ~9-12 independent GEMM pipelines per CU with decorrelated stalls.
// Per K-step: stage next tile (8 gload_lds) -> vmcnt(8) (retires CURRENT tile, issued
// one full iteration ago ≈ 450cyc cover) -> 8 ds_read_b128 -> 16 MFMA.
// WAR safe in program order (single wave). gload_lds->ds_read visibility = vmcnt retire.
// Expert-major XCD map kept: e = bid%8 (W[e] L2-resident), n-block fastest (A-panel reuse).
template<int Kd, bool G1>
__global__ __launch_bounds__(64, 3) void moe_gemm(
    const f16* __restrict__ A, const f16* __restrict__ Wt,
    const float* __restrict__ bias, const int* __restrict__ cnt,
    const int* __restrict__ bucket, const float* __restrict__ gates,
    f16* __restrict__ hbuf, float* __restrict__ out, int Ndim)
{
    int e   = (int)blockIdx.x & 7;
    int idx = (int)blockIdx.x >> 3;
    int nx  = Ndim >> 6;               // 64-wide n-blocks per expert
    int by  = idx / nx;
    int bx  = idx - by * nx;

    int count = min(cnt[e * CNT_PAD], Bsz);
    int m0 = by * 64;
    if (m0 >= count) return;
    int n0 = bx * 64;

    __shared__ alignas(16) f16 As[2][64 * 32];   // 2 x 4 KiB
    __shared__ alignas(16) f16 Bs[2][64 * 32];   // 2 x 4 KiB
    __shared__ int   s_rows[64];
    __shared__ float s_gates[64];

    int t = threadIdx.x;               // 0..63 == lane
    {
        int pos = min(m0 + t, count - 1);
        s_rows[t] = bucket[e * Bsz + pos];
        if constexpr (!G1) s_gates[t] = gates[e * Bsz + pos];
    }
    __syncthreads();                   // one-time (1-wave block: cheap)

    int scol = (t & 3) * 8;            // 16 B chunk within row
    // staging: instruction j covers rows j*16 + (t>>2), k-chunk scol
    const f16* agp[4];
    const f16* bgp[4];
    #pragma unroll
    for (int j = 0; j < 4; j++) {
        int srow = j * 16 + (t >> 2);
        int r = s_rows[srow];
        size_t arow = G1 ? (size_t)(r >> 1) : (size_t)r;
        agp[j] = A + arow * (size_t)Kd + scol;
        bgp[j] = Wt + ((size_t)e * Ndim + (n0 + srow)) * (size_t)Kd + scol;
    }

    int frow = t & 15;
    int fk   = (t >> 4) * 8;

    f32x4 acc[4][4] = {};

#define STAGE(buf) do { \
        _Pragma("unroll") \
        for (int j = 0; j < 4; j++) { \
            async_copy16(agp[j], &As[buf][j * 512]); agp[j] += 32; } \
        _Pragma("unroll") \
        for (int j = 0; j < 4; j++) { \
            async_copy16(bgp[j], &Bs[buf][j * 512]); bgp[j] += 32; } \
    } while (0)

#define COMPUTE(buf) do { \
        f16x8 af[4], bfr[4]; \
        _Pragma("unroll") \
        for (int i = 0; i < 4; i++) { \
            af[i]  = *(const f16x8*)(&As[buf][(i * 16 + frow) * 32 + fk]); \
            bfr[i] = *(const f16x8*)(&Bs[buf][(i * 16 + frow) * 32 + fk]); } \
        __builtin_amdgcn_s_setprio(1); \
        _Pragma("unroll") \
        for (int i = 0; i < 4; i++) \
            _Pragma("unroll") \
            for (int jj = 0; jj < 4; jj++) \
                acc[i][jj] = __builtin_amdgcn_mfma_f32_16x16x32_f16( \
                    af[i], bfr[jj], acc[i][jj], 0, 0, 0); \
        __builtin_amdgcn_s_setprio(0); \
    } while (0)

    // prologue: stage tile 0 -> buf 0 (8 loads outstanding)
    STAGE(0);

    // 2 tiles per iteration, named buffers (no dynamic indexing)
    for (int k0 = 0; k0 < Kd; k0 += 64) {
        // tile (k0): consume buf0; stage (k0+32) -> buf1 first (Kd%64==0 -> always valid)
        STAGE(1);
        WAIT_VM(8);        // retire tile k0's loads (issued one iteration ago)
        COMPUTE(0);
        // tile (k0+32): consume buf1; stage (k0+64) -> buf0 if it exists
        if (k0 + 64 < Kd) {
            STAGE(0);
            WAIT_VM(8);
        } else {
            WAIT_VM(0);
        }
        COMPUTE(1);
    }
#undef STAGE
#undef COMPUTE

    // epilogue: D row m = i*16 + (t>>4)*4 + reg, col n = n0 + jj*16 + frow
    float bv[4];
    #pragma unroll
    for (int jj = 0; jj < 4; jj++)
        bv[jj] = bias[e * Ndim + n0 + jj * 16 + frow];

    #pragma unroll
    for (int i = 0; i < 4; i++) {
        int mbase = i * 16 + (t >> 4) * 4;
        #pragma unroll
        for (int reg = 0; reg < 4; reg++) {
            int m = mbase + reg;
            if (m0 + m >= count) continue;
            int r = s_rows[m];
            if constexpr (G1) {
                f16* hrow = hbuf + (size_t)r * Hdim;
                #pragma unroll
                for (int jj = 0; jj < 4; jj++) {
                    int n = n0 + jj * 16 + frow;
                    float v = acc[i][jj][reg] + bv[jj];
                    hrow[n] = (f16)fmaxf(v, 0.f);
                }
            } else {
                int token = r >> 1;
                float g = s_gates[m];
                #pragma unroll
                for (int jj = 0; jj < 4; jj++) {
                    int n = n0 + jj * 16 + frow;
                    float v = g * (acc[i][jj][reg] + bv[jj]);
                    atomicAdd(&out[(size_t)token * Dout + n], v);
                }
            }
        }
    }
}

extern "C" void kernel_launch(void* const* d_in, const int* in_sizes, int n_in,
                              void* d_out, int out_size, void* d_ws, size_t ws_size,
                              hipStream_t stream) {
    const float* x   = (const float*)d_in[0];
    const float* rW  = (const float*)d_in[1];
    const float* rb  = (const float*)d_in[2];
    const float* W1  = (const float*)d_in[3];
    const float* b1  = (const float*)d_in[4];
    const float* W2  = (const float*)d_in[5];
    const float* b2  = (const float*)d_in[6];
    float* out   = (float*)d_out;
    float* probs = out + (size_t)Bsz * Dout;

    char* ws = (char*)d_ws;
    int*   cnt    = (int*)ws;                            // padded counters
    int*   bucket = (int*)(ws + 0x1000);                 // 512 KiB
    float* gates  = (float*)(ws + 0x90000);              // 512 KiB
    f16*   x16    = (f16*)(ws + 0x200000);               // 32 MiB
    f16*   w16    = (f16*)(ws + 0x2200000);              // 32 MiB (W1, then W2)
    f16*   hbuf   = (f16*)(ws + 0x4200000);              // 128 MiB

    hipMemsetAsync(cnt, 0, Ecnt * CNT_PAD * sizeof(int), stream);
    hipMemsetAsync(out, 0, (size_t)Bsz * Dout * sizeof(float), stream);

    cast_kernel<<<(Ecnt * Hdim * Din) / 1024, 256, 0, stream>>>(W1, w16);

    // router also writes x16 (fused cast)
    router_kernel<<<Bsz / 32, 256, 0, stream>>>(x, rW, rb, probs, cnt, bucket, gates, x16);

    // expert-major 1-D grids: e = bid%8 (one expert per XCD), n-block fastest
    int nb1 = Ecnt * (Bsz / 64) * (Hdim / 64);   // 65536
    moe_gemm<Din, true><<<nb1, 64, 0, stream>>>(
        x16, w16, b1, cnt, bucket, gates, hbuf, out, Hdim);

    cast_kernel<<<(Ecnt * Dout * Hdim) / 1024, 256, 0, stream>>>(W2, w16);

    int nb2 = Ecnt * (Bsz / 64) * (Dout / 64);   // 32768
    moe_gemm<Hdim, false><<<nb2, 64, 0, stream>>>(
        hbuf, w16, b2, cnt, bucket, gates, hbuf, out, Dout);
}

// Round 11
// 787.918 us; speedup vs baseline: 1.1466x; 1.1466x over previous
//
#include <hip/hip_runtime.h>
#include <hip/hip_bf16.h>

#define Bsz  16384
#define Din  1024
#define Dout 1024
#define Hdim 2048
#define Ecnt 8
#define CNT_PAD 32   // pad expert counters to 128 B apart

typedef _Float16 f16;
typedef _Float16 f16x8 __attribute__((ext_vector_type(8)));
typedef _Float16 f16x4 __attribute__((ext_vector_type(4)));
typedef float    f32x4 __attribute__((ext_vector_type(4)));

#define AS_GLOBAL __attribute__((address_space(1)))
#define AS_LDS    __attribute__((address_space(3)))

__device__ __forceinline__ void async_copy16(const void* gptr, void* lptr) {
    __builtin_amdgcn_global_load_lds(
        (const AS_GLOBAL unsigned int*)gptr,
        (AS_LDS unsigned int*)lptr, 16, 0, 0);
}

// ---------------- W pack: fp32 row-major -> f16 fragment-linear ----------------
// Output granule gid (8 f16 = 16 B): layout [e][nb][kb][f][l] with
//   nb = 128-wide n-block, kb = 32-wide k-block, f = 16-row fragment (0..7), l = lane.
//   element i of granule = W[e][nb*128 + f*16 + (l&15)][kb*32 + (l>>4)*8 + i]
// GEMM B-fragment read (wave w, frag jj, lane l) is then ONE coalesced 1-KB load at
//   Wp + e*N*K + nb*128*K + kb*4096 + ((w&1)*4+jj)*512 + l*8.
template<int Kd, int NdimT>
__global__ __launch_bounds__(256) void pack_kernel(
    const float* __restrict__ in, f16* __restrict__ outp)
{
    constexpr int KB = Kd / 32;
    constexpr int NB = NdimT / 128;
    int gid = blockIdx.x * 256 + threadIdx.x;
    int l    = gid & 63;
    int f    = (gid >> 6) & 7;
    int kb   = (gid >> 9) % KB;
    int rest = (gid >> 9) / KB;
    int nb   = rest % NB;
    int e    = rest / NB;
    int n = nb * 128 + f * 16 + (l & 15);
    int k = kb * 32 + (l >> 4) * 8;
    const float* src = in + ((size_t)e * NdimT + n) * Kd + k;
    float4 v0 = *(const float4*)(src);
    float4 v1 = *(const float4*)(src + 4);
    f16x8 o;
    o[0] = (f16)v0.x; o[1] = (f16)v0.y; o[2] = (f16)v0.z; o[3] = (f16)v0.w;
    o[4] = (f16)v1.x; o[5] = (f16)v1.y; o[6] = (f16)v1.z; o[7] = (f16)v1.w;
    *(f16x8*)(outp + (size_t)gid * 8) = o;
}

// ---------------- Router: logits -> softmax -> top-2 -> buckets (+ fused x->f16 cast) ----------------
__global__ __launch_bounds__(256) void router_kernel(
    const float* __restrict__ x, const float* __restrict__ rW,
    const float* __restrict__ rb, float* __restrict__ probs_out,
    int* __restrict__ cnt, int* __restrict__ bucket, float* __restrict__ gates,
    f16* __restrict__ x16)
{
    __shared__ float s_rw[Ecnt * Din];   // 32 KiB
    __shared__ int   s_e[64];
    __shared__ float s_g[64];
    __shared__ int   s_lpos[64];
    __shared__ int   s_lcnt[Ecnt];
    __shared__ int   s_base[Ecnt];

    int t = threadIdx.x;
    if (t < Ecnt) s_lcnt[t] = 0;
    for (int i = t; i < Ecnt * Din; i += 256) s_rw[i] = rW[i];
    __syncthreads();

    int wid = t >> 6, lane = t & 63;

    float rbv[8];
    #pragma unroll
    for (int e = 0; e < 8; e++) rbv[e] = rb[e];

    #pragma unroll 2
    for (int tt = 0; tt < 8; tt++) {
        int li = wid * 8 + tt;
        int token = blockIdx.x * 32 + li;
        const float* xrow = x + (size_t)token * Din;
        f16* xorow = x16 + (size_t)token * Din;

        float acc[8] = {0,0,0,0,0,0,0,0};
        #pragma unroll
        for (int i = 0; i < 4; i++) {
            int d = i * 256 + lane * 4;
            float4 xv = *(const float4*)(xrow + d);
            f16x4 xo;
            xo.x = (f16)xv.x; xo.y = (f16)xv.y; xo.z = (f16)xv.z; xo.w = (f16)xv.w;
            *(f16x4*)(xorow + d) = xo;
            #pragma unroll
            for (int e = 0; e < 8; e++) {
                float4 wv = *(const float4*)(s_rw + e * Din + d);
                acc[e] += xv.x * wv.x + xv.y * wv.y + xv.z * wv.z + xv.w * wv.w;
            }
        }
        #pragma unroll
        for (int e = 0; e < 8; e++) {
            #pragma unroll
            for (int m = 1; m < 64; m <<= 1) acc[e] += __shfl_xor(acc[e], m, 64);
        }

        float p[8], mx = -1e30f;
        #pragma unroll
        for (int e = 0; e < 8; e++) { p[e] = acc[e] + rbv[e]; mx = fmaxf(mx, p[e]); }
        float s = 0.f;
        #pragma unroll
        for (int e = 0; e < 8; e++) { p[e] = expf(p[e] - mx); s += p[e]; }
        float inv = 1.f / s;
        #pragma unroll
        for (int e = 0; e < 8; e++) p[e] *= inv;

        if (lane == 0) {
            float* po = probs_out + (size_t)token * Ecnt;
            #pragma unroll
            for (int e = 0; e < 8; e++) po[e] = p[e];
            int i0 = 0; float v0 = p[0];
            #pragma unroll
            for (int e = 1; e < 8; e++) if (p[e] > v0) { v0 = p[e]; i0 = e; }
            int i1 = -1; float v1 = -1e30f;
            #pragma unroll
            for (int e = 0; e < 8; e++) if (e != i0 && p[e] > v1) { v1 = p[e]; i1 = e; }
            float invs = 1.f / (v0 + v1);
            s_e[2 * li]     = i0;  s_g[2 * li]     = v0 * invs;
            s_e[2 * li + 1] = i1;  s_g[2 * li + 1] = v1 * invs;
        }
    }
    __syncthreads();

    if (t < 64) s_lpos[t] = atomicAdd(&s_lcnt[s_e[t]], 1);
    __syncthreads();
    if (t < Ecnt) s_base[t] = atomicAdd(&cnt[t * CNT_PAD], s_lcnt[t]);
    __syncthreads();
    if (t < 64) {
        int e = s_e[t];
        int pos = s_base[e] + s_lpos[t];
        int li = t >> 1;
        int token = blockIdx.x * 32 + li;
        bucket[e * Bsz + pos] = token * 2 + (t & 1);
        gates [e * Bsz + pos] = s_g[t];
    }
}

// ---------------- MFMA grouped GEMM: 128x128; A LDS-dbuf, B coalesced global->reg ----------------
// R11: LDS pipe measured ~52% busy (dominant). B now bypasses LDS entirely via the
// fragment-linear pre-pack: per wave per K-step, 4x coalesced 1-KB global_load_dwordx4
// from L2-resident W[e] straight to registers (named bE/bO sets, x2-unrolled loop).
// LDS carries only gathered A: reads 32->16 KB, writes 16->8 KB per block-step,
// bank conflicts halve. K-loop structure otherwise the proven R6/R9 2-phase dbuf.
template<int Kd, bool G1>
__global__ __launch_bounds__(256) void moe_gemm(
    const f16* __restrict__ A, const f16* __restrict__ Wp,
    const float* __restrict__ bias, const int* __restrict__ cnt,
    const int* __restrict__ bucket, const float* __restrict__ gates,
    f16* __restrict__ hbuf, float* __restrict__ out, int Ndim)
{
    int e   = (int)blockIdx.x & 7;
    int idx = (int)blockIdx.x >> 3;
    int nx  = Ndim >> 7;
    int by  = idx / nx;
    int bx  = idx - by * nx;

    int count = min(cnt[e * CNT_PAD], Bsz);
    int m0 = by * 128;
    if (m0 >= count) return;
    int n0 = bx * 128;

    __shared__ alignas(16) f16 As[2][128 * 32];   // 2 x 8 KiB (A only)
    __shared__ int   s_rows[128];
    __shared__ float s_gates[128];

    int t = threadIdx.x;
    if (t < 128) {
        int pos = min(m0 + t, count - 1);
        s_rows[t] = bucket[e * Bsz + pos];
        if constexpr (!G1) s_gates[t] = gates[e * Bsz + pos];
    }
    __syncthreads();

    int wave = t >> 6, lane = t & 63;
    int scol = (lane & 3) * 8;            // 16 B chunk within row

    const f16* agp[2];
    #pragma unroll
    for (int j = 0; j < 2; j++) {
        int srow = wave * 32 + j * 16 + (lane >> 2);
        int r = s_rows[srow];
        size_t arow = G1 ? (size_t)(r >> 1) : (size_t)r;
        agp[j] = A + arow * Kd + scol;
    }

    int m_w = (wave >> 1) * 64;           // wave's 64x64 sub-tile
    int n_w = (wave & 1) * 64;
    int frow = lane & 15;
    int fk   = (lane >> 4) * 8;

    // B fragment-linear pointer: [e][nb=bx][kb][f][l]; per k-step advance 4096 f16
    const f16* bq = Wp + (size_t)e * Ndim * Kd + (size_t)bx * (128 * Kd)
                    + (size_t)((wave & 1) * 4) * 512 + (size_t)lane * 8;

    f32x4 acc[4][4] = {};
    f16x8 bE[4], bO[4];

#define STAGE_A(buf) do { \
        _Pragma("unroll") \
        for (int j = 0; j < 2; j++) { \
            async_copy16(agp[j], &As[buf][(wave * 32 + j * 16) * 32]); \
            agp[j] += 32; } \
    } while (0)

#define LOAD_B(dst) do { \
        _Pragma("unroll") \
        for (int jj = 0; jj < 4; jj++) dst[jj] = *(const f16x8*)(bq + jj * 512); \
        bq += 4096; \
    } while (0)

#define COMPUTE(buf, bset) do { \
        f16x8 af[4]; \
        _Pragma("unroll") \
        for (int i = 0; i < 4; i++) \
            af[i] = *(const f16x8*)(&As[buf][(m_w + i * 16 + frow) * 32 + fk]); \
        __builtin_amdgcn_s_setprio(1); \
        _Pragma("unroll") \
        for (int i = 0; i < 4; i++) \
            _Pragma("unroll") \
            for (int jj = 0; jj < 4; jj++) \
                acc[i][jj] = __builtin_amdgcn_mfma_f32_16x16x32_f16( \
                    af[i], bset[jj], acc[i][jj], 0, 0, 0); \
        __builtin_amdgcn_s_setprio(0); \
    } while (0)

    // prologue: stage A(0) -> buf0, load B(0) -> bE
    STAGE_A(0);
    LOAD_B(bE);
    __syncthreads();   // tile 0 resident (barrier drains vmcnt)

    for (int k0 = 0; k0 < Kd; k0 += 64) {
        // half 0: consume As[0] + bE; prefetch k0+32 (always exists: Kd % 64 == 0)
        STAGE_A(1);
        LOAD_B(bO);
        COMPUTE(0, bE);
        __syncthreads();
        // half 1: consume As[1] + bO; prefetch k0+64 if it exists
        if (k0 + 64 < Kd) {
            STAGE_A(0);
            LOAD_B(bE);
        }
        COMPUTE(1, bO);
        __syncthreads();
    }
#undef STAGE_A
#undef LOAD_B
#undef COMPUTE

    // epilogue: D row m = m_w + i*16 + (lane>>4)*4 + reg, col n = n0 + n_w + jj*16 + frow
    float bv[4];
    #pragma unroll
    for (int jj = 0; jj < 4; jj++)
        bv[jj] = bias[e * Ndim + n0 + n_w + jj * 16 + frow];

    #pragma unroll
    for (int i = 0; i < 4; i++) {
        int mbase = m_w + i * 16 + (lane >> 4) * 4;
        #pragma unroll
        for (int reg = 0; reg < 4; reg++) {
            int m = mbase + reg;
            if (m0 + m >= count) continue;
            int r = s_rows[m];
            if constexpr (G1) {
                f16* hrow = hbuf + (size_t)r * Hdim;
                #pragma unroll
                for (int jj = 0; jj < 4; jj++) {
                    int n = n0 + n_w + jj * 16 + frow;
                    float v = acc[i][jj][reg] + bv[jj];
                    hrow[n] = (f16)fmaxf(v, 0.f);
                }
            } else {
                int token = r >> 1;
                float g = s_gates[m];
                #pragma unroll
                for (int jj = 0; jj < 4; jj++) {
                    int n = n0 + n_w + jj * 16 + frow;
                    float v = g * (acc[i][jj][reg] + bv[jj]);
                    atomicAdd(&out[(size_t)token * Dout + n], v);
                }
            }
        }
    }
}

extern "C" void kernel_launch(void* const* d_in, const int* in_sizes, int n_in,
                              void* d_out, int out_size, void* d_ws, size_t ws_size,
                              hipStream_t stream) {
    const float* x   = (const float*)d_in[0];
    const float* rW  = (const float*)d_in[1];
    const float* rb  = (const float*)d_in[2];
    const float* W1  = (const float*)d_in[3];
    const float* b1  = (const float*)d_in[4];
    const float* W2  = (const float*)d_in[5];
    const float* b2  = (const float*)d_in[6];
    float* out   = (float*)d_out;
    float* probs = out + (size_t)Bsz * Dout;

    char* ws = (char*)d_ws;
    int*   cnt    = (int*)ws;                            // padded counters
    int*   bucket = (int*)(ws + 0x1000);                 // 512 KiB
    float* gates  = (float*)(ws + 0x90000);              // 512 KiB
    f16*   x16    = (f16*)(ws + 0x200000);               // 32 MiB
    f16*   w16    = (f16*)(ws + 0x2200000);              // 32 MiB (packed W1, then W2)
    f16*   hbuf   = (f16*)(ws + 0x4200000);              // 128 MiB

    hipMemsetAsync(cnt, 0, Ecnt * CNT_PAD * sizeof(int), stream);
    hipMemsetAsync(out, 0, (size_t)Bsz * Dout * sizeof(float), stream);

    // W1: fp32 [E][Hdim][Din] -> fragment-linear f16 (N=Hdim, K=Din)
    pack_kernel<Din, Hdim><<<(Ecnt * Hdim * Din) / 2048, 256, 0, stream>>>(W1, w16);

    // router also writes x16 (fused cast)
    router_kernel<<<Bsz / 32, 256, 0, stream>>>(x, rW, rb, probs, cnt, bucket, gates, x16);

    // expert-major 1-D grids: e = bid%8 (one expert per XCD), n-block fastest
    int nb1 = Ecnt * (Bsz / 128) * (Hdim / 128);   // 16384
    moe_gemm<Din, true><<<nb1, 256, 0, stream>>>(
        x16, w16, b1, cnt, bucket, gates, hbuf, out, Hdim);

    // W2: fp32 [E][Dout][Hdim] -> fragment-linear f16 (N=Dout, K=Hdim); reuses w16
    pack_kernel<Hdim, Dout><<<(Ecnt * Dout * Hdim) / 2048, 256, 0, stream>>>(W2, w16);

    int nb2 = Ecnt * (Bsz / 128) * (Dout / 128);   // 8192
    moe_gemm<Hdim, false><<<nb2, 256, 0, stream>>>(
        hbuf, w16, b2, cnt, bucket, gates, hbuf, out, Dout);
}